// Round 4
// baseline (485.670 us; speedup 1.0000x reference)
//
#include <hip/hip_runtime.h>
#include <hip/hip_bf16.h>

typedef unsigned short u16;
typedef unsigned int u32;
typedef __attribute__((ext_vector_type(8))) short short8;
typedef __attribute__((ext_vector_type(4))) float f32x4;

#define NB 64
#define NS 2048
#define ND 512
#define NU 256

__device__ __forceinline__ u16 f2b(float f) {
    u32 x = __float_as_uint(f);
    u32 r = (x + 0x7FFFu + ((x >> 16) & 1u)) >> 16;   // round-to-nearest-even
    return (u16)r;
}
__device__ __forceinline__ u32 pk2(float lo, float hi) {
    // packs to [hi:lo] u32; compiles to v_cvt_pk_bf16_f32 on gfx950
    __hip_bfloat162 h = __float22bfloat162_rn(float2{lo, hi});
    return *(u32*)&h;
}
__device__ __forceinline__ float fast_tanh(float x) {
    float e = __expf(2.0f * x);
    return 1.0f - 2.0f / (e + 1.0f);
}

// ---------------------------------------------------------------------------
// Kernel 1: cb[b][u] = sum_d q[b][d]*W2[d][u] + b1[u] + b2[u]   (all fp32)
// ---------------------------------------------------------------------------
__global__ __launch_bounds__(256) void cbias_kernel(
    const float* __restrict__ q, const float* __restrict__ W2,
    const float* __restrict__ b1, const float* __restrict__ b2,
    float* __restrict__ cb)
{
    int b = blockIdx.x, u = threadIdx.x;
    __shared__ float qs[ND];
    qs[u]       = q[b * ND + u];
    qs[u + 256] = q[b * ND + u + 256];
    __syncthreads();
    float acc = 0.f;
#pragma unroll 8
    for (int d = 0; d < ND; d++)
        acc += qs[d] * W2[d * NU + u];
    cb[b * NU + u] = acc + b1[u] + b2[u];
}

// ---------------------------------------------------------------------------
// Kernel 2: W1Tc[kc][u][kk] = bf16(W1[kc*64+kk][u])  (K-chunked bf16 layout,
// kc in [0,8), kk in [0,64) — B-staging reads become fully contiguous 32 KB)
// ---------------------------------------------------------------------------
__global__ __launch_bounds__(256) void transpose_kernel(
    const float* __restrict__ W1, u16* __restrict__ W1Tc)
{
    __shared__ float tile[64][65];
    int k0 = blockIdx.x * 64;   // 8 tiles along D (kc = blockIdx.x)
    int u0 = blockIdx.y * 64;   // 4 tiles along U
    for (int i = threadIdx.x; i < 4096; i += 256) {
        int r = i >> 6, c = i & 63;          // r: k-local, c: u-local
        tile[r][c] = W1[(k0 + r) * NU + u0 + c];
    }
    __syncthreads();
    for (int i = threadIdx.x; i < 4096; i += 256) {
        int r = i >> 6, c = i & 63;          // r: u-local, c: k-local
        W1Tc[blockIdx.x * (NU * 64) + (u0 + r) * 64 + c] = f2b(tile[c][r]);
    }
}

// ---------------------------------------------------------------------------
// Kernel 3: score GEMM, tile M=64 x N=256, BK=64, 256 thr = 4 waves (all in N).
// 3 blocks/CU resident (LDS 48.5 KB, VGPR capped by launch_bounds(256,3)).
// ---------------------------------------------------------------------------
__global__ __launch_bounds__(256, 3) void score_kernel(
    const float* __restrict__ values, // [64][2048][512] fp32
    const u16* __restrict__ W1Tc,     // [8][256][64] bf16 K-chunked
    const float* __restrict__ cb,     // [64][256]
    const float* __restrict__ V,      // [256]
    float* __restrict__ scores)       // [64*2048]
{
    const int tid  = threadIdx.x;
    const int lane = tid & 63;
    const int wn   = tid >> 6;        // 0..3 (N dim)
    const int m16  = lane & 15;
    const int quad = lane >> 4;

    const int mblk = blockIdx.x;              // 0..2047 (32 M-tiles per batch)
    const int b    = mblk >> 5;
    const size_t base_row = (size_t)mblk * 64;

    // stride 72 u16 (=36 dw): per-16-lane-phase bank groups are 2-way -> free
    __shared__ u16 At[64][72];
    __shared__ u16 Bt[256][72];
    __shared__ float cbs[NU];
    __shared__ float Vs[NU];
    __shared__ float rowsum[64];

    cbs[tid] = cb[b * NU + tid];
    Vs[tid]  = V[tid];
    if (tid < 64) rowsum[tid] = 0.f;

    f32x4 acc[4][4] = {};

    const float* Abase = values + base_row * ND;
    const int arow = tid >> 2, aseg = tid & 3;   // 64 rows x 4 16-float chunks

    for (int kc = 0; kc < 8; kc++) {
        const int k0 = kc * 64;
        // stage A: 64 x 64 fp32 -> bf16 (4 float4 loads, 8 pk-cvt, 2 b128 st)
        {
            const float* src = Abase + (size_t)arow * ND + k0 + aseg * 16;
            float4 v0 = ((const float4*)src)[0];
            float4 v1 = ((const float4*)src)[1];
            float4 v2 = ((const float4*)src)[2];
            float4 v3 = ((const float4*)src)[3];
            uint4 q0, q1;
            q0.x = pk2(v0.x, v0.y); q0.y = pk2(v0.z, v0.w);
            q0.z = pk2(v1.x, v1.y); q0.w = pk2(v1.z, v1.w);
            q1.x = pk2(v2.x, v2.y); q1.y = pk2(v2.z, v2.w);
            q1.z = pk2(v3.x, v3.y); q1.w = pk2(v3.z, v3.w);
            *(uint4*)&At[arow][aseg * 16]     = q0;
            *(uint4*)&At[arow][aseg * 16 + 8] = q1;
        }
        // stage B: 256 x 64 bf16 (contiguous 32 KB chunk; thread t = row u=t)
        {
            const uint4* bsrc = (const uint4*)(W1Tc + (size_t)kc * (NU * 64) + tid * 64);
#pragma unroll
            for (int j = 0; j < 8; j++)
                *(uint4*)&Bt[tid][j * 8] = bsrc[j];
        }
        __syncthreads();

#pragma unroll
        for (int kh = 0; kh < 2; kh++) {
            short8 afr[4], bfr[4];
#pragma unroll
            for (int rb = 0; rb < 4; rb++)
                afr[rb] = *(const short8*)&At[rb * 16 + m16][kh * 32 + quad * 8];
#pragma unroll
            for (int cbk = 0; cbk < 4; cbk++)
                bfr[cbk] = *(const short8*)&Bt[wn * 64 + cbk * 16 + m16][kh * 32 + quad * 8];
#pragma unroll
            for (int rb = 0; rb < 4; rb++)
#pragma unroll
                for (int cbk = 0; cbk < 4; cbk++)
                    acc[rb][cbk] = __builtin_amdgcn_mfma_f32_16x16x32_bf16(
                        afr[rb], bfr[cbk], acc[rb][cbk], 0, 0, 0);
        }
        __syncthreads();
    }

    // Epilogue: s(row) += sum_c tanh(pv + cb[c]) * V[c] over this wave's 64 c
    float cbv[4], vv[4];
#pragma unroll
    for (int cbk = 0; cbk < 4; cbk++) {
        int c = wn * 64 + cbk * 16 + m16;
        cbv[cbk] = cbs[c];
        vv[cbk]  = Vs[c];
    }
#pragma unroll
    for (int rb = 0; rb < 4; rb++) {
#pragma unroll
        for (int i = 0; i < 4; i++) {
            float s = 0.f;
#pragma unroll
            for (int cbk = 0; cbk < 4; cbk++)
                s += fast_tanh(acc[rb][cbk][i] + cbv[cbk]) * vv[cbk];
            s += __shfl_xor(s, 1, 64);
            s += __shfl_xor(s, 2, 64);
            s += __shfl_xor(s, 4, 64);
            s += __shfl_xor(s, 8, 64);
            if (m16 == 0)
                atomicAdd(&rowsum[rb * 16 + quad * 4 + i], s);
        }
    }
    __syncthreads();
    if (tid < 64) scores[base_row + tid] = rowsum[tid];
}

// ---------------------------------------------------------------------------
// Kernel 4: softmax over S per batch (bV dropped: uniform shift)
// ---------------------------------------------------------------------------
__global__ __launch_bounds__(256) void softmax_kernel(
    const float* __restrict__ scores, float* __restrict__ attn)
{
    int b = blockIdx.x, tid = threadIdx.x;
    __shared__ float red[256];
    const float* s = scores + (size_t)b * NS;
    float v[8];
    float mx = -1e30f;
#pragma unroll
    for (int i = 0; i < 8; i++) { v[i] = s[tid + i * 256]; mx = fmaxf(mx, v[i]); }
    red[tid] = mx; __syncthreads();
    for (int off = 128; off > 0; off >>= 1) {
        if (tid < off) red[tid] = fmaxf(red[tid], red[tid + off]);
        __syncthreads();
    }
    mx = red[0]; __syncthreads();
    float sum = 0.f;
#pragma unroll
    for (int i = 0; i < 8; i++) { v[i] = __expf(v[i] - mx); sum += v[i]; }
    red[tid] = sum; __syncthreads();
    for (int off = 128; off > 0; off >>= 1) {
        if (tid < off) red[tid] += red[tid + off];
        __syncthreads();
    }
    float inv = 1.0f / red[0];
#pragma unroll
    for (int i = 0; i < 8; i++) attn[(size_t)b * NS + tid + i * 256] = v[i] * inv;
}

// ---------------------------------------------------------------------------
// Kernel 5: context partials over 64-row chunks; 2048 blocks (8/CU), 8 float4
// loads in flight per thread, per-inst 512 B contiguous wave segments.
// ---------------------------------------------------------------------------
__global__ __launch_bounds__(256) void context_kernel(
    const float* __restrict__ values, const float* __restrict__ attn,
    float* __restrict__ partial)
{
    int sc = blockIdx.x, b = blockIdx.y, tid = threadIdx.x;
    int srow = tid >> 5;              // 0..7
    int dcol = tid & 31;
    __shared__ float at[64];
    __shared__ float part[8][ND];
    if (tid < 64) at[tid] = attn[(size_t)b * NS + sc * 64 + tid];
    __syncthreads();
    float acc[16] = {};
    const float* vb = values + ((size_t)b * NS + (size_t)sc * 64) * ND;
#pragma unroll 2
    for (int i = 0; i < 8; i++) {
        int sl = i * 8 + srow;
        float a = at[sl];
        const float* row = vb + (size_t)sl * ND + dcol * 4;
        float4 r0 = *(const float4*)(row);
        float4 r1 = *(const float4*)(row + 128);
        float4 r2 = *(const float4*)(row + 256);
        float4 r3 = *(const float4*)(row + 384);
        acc[0]  += a * r0.x; acc[1]  += a * r0.y; acc[2]  += a * r0.z; acc[3]  += a * r0.w;
        acc[4]  += a * r1.x; acc[5]  += a * r1.y; acc[6]  += a * r1.z; acc[7]  += a * r1.w;
        acc[8]  += a * r2.x; acc[9]  += a * r2.y; acc[10] += a * r2.z; acc[11] += a * r2.w;
        acc[12] += a * r3.x; acc[13] += a * r3.y; acc[14] += a * r3.z; acc[15] += a * r3.w;
    }
#pragma unroll
    for (int j = 0; j < 4; j++)
        *(float4*)&part[srow][j * 128 + dcol * 4] =
            float4{acc[j*4], acc[j*4+1], acc[j*4+2], acc[j*4+3]};
    __syncthreads();
    for (int d = tid; d < ND; d += 256) {
        float s = 0.f;
#pragma unroll
        for (int r = 0; r < 8; r++) s += part[r][d];
        partial[((size_t)b * 32 + sc) * ND + d] = s;
    }
}

// ---------------------------------------------------------------------------
// Kernel 6: out[b][d] = sum_sc partial[b][sc][d]   (fp32 output)
// ---------------------------------------------------------------------------
__global__ __launch_bounds__(256) void finalize_kernel(
    const float* __restrict__ partial, float* __restrict__ out)
{
    int idx = blockIdx.x * 256 + threadIdx.x;  // 0..32767
    int b = idx >> 9, d = idx & 511;
    float s = 0.f;
#pragma unroll
    for (int sc = 0; sc < 32; sc++)
        s += partial[((size_t)b * 32 + sc) * ND + d];
    out[idx] = s;
}

// ---------------------------------------------------------------------------
extern "C" void kernel_launch(void* const* d_in, const int* in_sizes, int n_in,
                              void* d_out, int out_size, void* d_ws, size_t ws_size,
                              hipStream_t stream)
{
    const float* q      = (const float*)d_in[0];   // [64][512]
    const float* values = (const float*)d_in[1];   // [64][2048][512]
    const float* W1     = (const float*)d_in[2];   // [512][256]
    const float* b1     = (const float*)d_in[3];   // [256]
    const float* W2     = (const float*)d_in[4];   // [512][256]
    const float* b2     = (const float*)d_in[5];   // [256]
    const float* V      = (const float*)d_in[6];   // [256]
    // d_in[7] = bV: uniform score shift -> softmax invariant, unused.

    char* ws = (char*)d_ws;
    float* cb      = (float*)(ws);                       //  65536 B
    u16*   W1Tc    = (u16*)  (ws + 65536);               // 262144 B
    float* scores  = (float*)(ws + 327680);              // 524288 B
    float* attn    = (float*)(ws + 851968);              // 524288 B
    float* partial = (float*)(ws + 1376256);             // 4 MB (64*32*512*4)

    hipLaunchKernelGGL(cbias_kernel, dim3(64), dim3(256), 0, stream, q, W2, b1, b2, cb);
    hipLaunchKernelGGL(transpose_kernel, dim3(8, 4), dim3(256), 0, stream, W1, W1Tc);
    hipLaunchKernelGGL(score_kernel, dim3(2048), dim3(256), 0, stream,
                       values, W1Tc, cb, V, scores);
    hipLaunchKernelGGL(softmax_kernel, dim3(64), dim3(256), 0, stream, scores, attn);
    hipLaunchKernelGGL(context_kernel, dim3(32, 64), dim3(256), 0, stream,
                       values, attn, partial);
    hipLaunchKernelGGL(finalize_kernel, dim3(128), dim3(256), 0, stream,
                       partial, (float*)d_out);
}

// Round 5
// 463.044 us; speedup vs baseline: 1.0489x; 1.0489x over previous
//
#include <hip/hip_runtime.h>
#include <hip/hip_bf16.h>

typedef unsigned short u16;
typedef unsigned int u32;
typedef __attribute__((ext_vector_type(8))) short short8;
typedef __attribute__((ext_vector_type(4))) float f32x4;

#define NB 64
#define NS 2048
#define ND 512
#define NU 256
// Afull row stride in u16: 512 + 8 pad -> 260 dwords/row (4 mod 32 banks: 2-way on b128, free)
#define ASTR 520

__device__ __forceinline__ u16 f2b(float f) {
    u32 x = __float_as_uint(f);
    u32 r = (x + 0x7FFFu + ((x >> 16) & 1u)) >> 16;   // RNE
    return (u16)r;
}
__device__ __forceinline__ u32 pk2(float lo, float hi) {
    __hip_bfloat162 h = __float22bfloat162_rn(float2{lo, hi});
    return *(u32*)&h;
}
__device__ __forceinline__ float fast_tanh(float x) {
    float e = __expf(2.0f * x);
    return 1.0f - 2.0f / (e + 1.0f);
}

// ---------------------------------------------------------------------------
// Kernel 1: cb[b][u] = sum_d q[b][d]*W2[d][u] + b1[u] + b2[u]   (all fp32)
// ---------------------------------------------------------------------------
__global__ __launch_bounds__(256) void cbias_kernel(
    const float* __restrict__ q, const float* __restrict__ W2,
    const float* __restrict__ b1, const float* __restrict__ b2,
    float* __restrict__ cb)
{
    int b = blockIdx.x, u = threadIdx.x;
    __shared__ float qs[ND];
    qs[u]       = q[b * ND + u];
    qs[u + 256] = q[b * ND + u + 256];
    __syncthreads();
    float acc = 0.f;
#pragma unroll 8
    for (int d = 0; d < ND; d++)
        acc += qs[d] * W2[d * NU + u];
    cb[b * NU + u] = acc + b1[u] + b2[u];
}

// ---------------------------------------------------------------------------
// Kernel 2: W1Tc[kc][u][kk] = bf16(W1[kc*64+kk][u])  (K-chunked bf16 layout)
// 256 KB total -> L2-resident; fused kernel reads B-fragments from it directly
// ---------------------------------------------------------------------------
__global__ __launch_bounds__(256) void transpose_kernel(
    const float* __restrict__ W1, u16* __restrict__ W1Tc)
{
    __shared__ float tile[64][65];
    int k0 = blockIdx.x * 64;
    int u0 = blockIdx.y * 64;
    for (int i = threadIdx.x; i < 4096; i += 256) {
        int r = i >> 6, c = i & 63;
        tile[r][c] = W1[(k0 + r) * NU + u0 + c];
    }
    __syncthreads();
    for (int i = threadIdx.x; i < 4096; i += 256) {
        int r = i >> 6, c = i & 63;
        W1Tc[blockIdx.x * (NU * 64) + (u0 + r) * 64 + c] = f2b(tile[c][r]);
    }
}

// ---------------------------------------------------------------------------
// Kernel 3 (FUSED): per (b, 64-row chunk):
//   phase 1: pv = values_chunk @ W1 (MFMA, bf16), A-tile persists in LDS
//   phase 2: s[row] = sum_u tanh(pv+cb)*V[u]; chunk-local online softmax
//   phase 3: ctx_partial[d] = sum_row exp(s-m_loc) * values[row][d]  (from LDS)
// values is read from HBM exactly ONCE.
// 256 thr = 4 waves (all in N: each wave 64 u-cols). LDS ~69.4 KB -> 2 blk/CU.
// ---------------------------------------------------------------------------
__global__ __launch_bounds__(256, 2) void fused_kernel(
    const float* __restrict__ values, // [64][2048][512] fp32
    const u16* __restrict__ W1Tc,     // [8][256][64] bf16
    const float* __restrict__ cb,     // [64][256]
    const float* __restrict__ V,      // [256]
    float* __restrict__ ctxp,         // [64*32][512] chunk context partials
    float2* __restrict__ meta)        // [64*32] (m_loc, l_loc)
{
    const int tid  = threadIdx.x;
    const int lane = tid & 63;
    const int wn   = tid >> 6;        // 0..3 (N dim)
    const int m16  = lane & 15;
    const int quad = lane >> 4;

    const int mblk = blockIdx.x;              // 0..2047
    const int b    = mblk >> 5;               // 32 chunks per batch
    const size_t base_row = (size_t)mblk * 64;

    __shared__ u16 Afull[64][ASTR];           // 66.6 KB, persists all phases
    __shared__ float cbs[NU];
    __shared__ float Vs[NU];
    __shared__ float rowsum[64];
    __shared__ float wsm[64];
    __shared__ float mred[2];

    cbs[tid] = cb[b * NU + tid];
    Vs[tid]  = V[tid];
    if (tid < 64) rowsum[tid] = 0.f;

    f32x4 acc[4][4] = {};

    const float* asrc = values + (base_row + (tid >> 2)) * ND + (tid & 3) * 16;
    const int arow = tid >> 2, acol = (tid & 3) * 16;

    // preload kc=0 A-chunk into regs
    float4 v0 = ((const float4*)asrc)[0];
    float4 v1 = ((const float4*)asrc)[1];
    float4 v2 = ((const float4*)asrc)[2];
    float4 v3 = ((const float4*)asrc)[3];

    for (int kc = 0; kc < 8; kc++) {
        // pack current regs -> LDS column block kc*64 (disjoint from kc-1 reads)
        {
            uint4 q0, q1;
            q0.x = pk2(v0.x, v0.y); q0.y = pk2(v0.z, v0.w);
            q0.z = pk2(v1.x, v1.y); q0.w = pk2(v1.z, v1.w);
            q1.x = pk2(v2.x, v2.y); q1.y = pk2(v2.z, v2.w);
            q1.z = pk2(v3.x, v3.y); q1.w = pk2(v3.z, v3.w);
            *(uint4*)&Afull[arow][kc * 64 + acol]     = q0;
            *(uint4*)&Afull[arow][kc * 64 + acol + 8] = q1;
        }
        __syncthreads();
        // prefetch next A-chunk (overlaps MFMA below)
        if (kc < 7) {
            const float* nsrc = asrc + (kc + 1) * 64;
            v0 = ((const float4*)nsrc)[0];
            v1 = ((const float4*)nsrc)[1];
            v2 = ((const float4*)nsrc)[2];
            v3 = ((const float4*)nsrc)[3];
        }
        // B fragments straight from global (W1Tc is L2/L1-hot, 16 KB per kc)
        short8 bfr[2][4];
#pragma unroll
        for (int kh = 0; kh < 2; kh++)
#pragma unroll
            for (int cbk = 0; cbk < 4; cbk++)
                bfr[kh][cbk] = *(const short8*)(W1Tc + (size_t)kc * (NU * 64)
                                + (wn * 64 + cbk * 16 + m16) * 64 + kh * 32 + quad * 8);
#pragma unroll
        for (int kh = 0; kh < 2; kh++) {
            short8 afr[4];
#pragma unroll
            for (int rb = 0; rb < 4; rb++)
                afr[rb] = *(const short8*)&Afull[rb * 16 + m16][kc * 64 + kh * 32 + quad * 8];
#pragma unroll
            for (int rb = 0; rb < 4; rb++)
#pragma unroll
                for (int cbk = 0; cbk < 4; cbk++)
                    acc[rb][cbk] = __builtin_amdgcn_mfma_f32_16x16x32_bf16(
                        afr[rb], bfr[kh][cbk], acc[rb][cbk], 0, 0, 0);
        }
        __syncthreads();
    }

    // ---- phase 2: scores + chunk-local softmax stats ----
    float cbv[4], vv[4];
#pragma unroll
    for (int cbk = 0; cbk < 4; cbk++) {
        int c = wn * 64 + cbk * 16 + m16;
        cbv[cbk] = cbs[c];
        vv[cbk]  = Vs[c];
    }
#pragma unroll
    for (int rb = 0; rb < 4; rb++) {
#pragma unroll
        for (int i = 0; i < 4; i++) {
            float s = 0.f;
#pragma unroll
            for (int cbk = 0; cbk < 4; cbk++)
                s += fast_tanh(acc[rb][cbk][i] + cbv[cbk]) * vv[cbk];
            s += __shfl_xor(s, 1, 64);
            s += __shfl_xor(s, 2, 64);
            s += __shfl_xor(s, 4, 64);
            s += __shfl_xor(s, 8, 64);
            if (m16 == 0)
                atomicAdd(&rowsum[rb * 16 + quad * 4 + i], s);
        }
    }
    __syncthreads();

    if (tid < 64) {                    // wave 0: softmax partials via shuffles
        float s = rowsum[tid];
        float m = s;
        m = fmaxf(m, __shfl_xor(m, 1, 64));
        m = fmaxf(m, __shfl_xor(m, 2, 64));
        m = fmaxf(m, __shfl_xor(m, 4, 64));
        m = fmaxf(m, __shfl_xor(m, 8, 64));
        m = fmaxf(m, __shfl_xor(m, 16, 64));
        m = fmaxf(m, __shfl_xor(m, 32, 64));
        float w = __expf(s - m);
        wsm[tid] = w;
        float l = w;
        l += __shfl_xor(l, 1, 64);
        l += __shfl_xor(l, 2, 64);
        l += __shfl_xor(l, 4, 64);
        l += __shfl_xor(l, 8, 64);
        l += __shfl_xor(l, 16, 64);
        l += __shfl_xor(l, 32, 64);
        if (tid == 0) { mred[0] = m; mred[1] = l; }
    }
    __syncthreads();

    // ---- phase 3: ctx_partial[d] = sum_row wsm[row] * Afull[row][d] ----
    {
        const u32* adw = (const u32*)&Afull[0][0];   // row stride 260 dwords
        float a0 = 0.f, a1 = 0.f;
#pragma unroll 8
        for (int r = 0; r < 64; r++) {
            u32 pk = adw[r * (ASTR / 2) + tid];       // 2-way broadcast-free
            float lo = __uint_as_float(pk << 16);
            float hi = __uint_as_float(pk & 0xFFFF0000u);
            float wt = wsm[r];
            a0 += wt * lo;
            a1 += wt * hi;
        }
        float* dst = ctxp + (size_t)mblk * ND + tid * 2;
        dst[0] = a0;
        dst[1] = a1;
    }
    if (tid == 0) meta[mblk] = float2{mred[0], mred[1]};
}

// ---------------------------------------------------------------------------
// Kernel 4: combine chunk partials: out[b][d] = sum_c e^{m_c-M} ctx_c[d] / L,
// L = sum_c e^{m_c-M} l_c.  64 blocks x 256 thr, reads 4 MB.
// ---------------------------------------------------------------------------
__global__ __launch_bounds__(256) void combine_kernel(
    const float* __restrict__ ctxp, const float2* __restrict__ meta,
    float* __restrict__ out)
{
    int b = blockIdx.x, tid = threadIdx.x;
    __shared__ float wc[32];
    __shared__ float Ls;
    if (tid == 0) {
        float M = -1e30f;
        for (int c = 0; c < 32; c++) M = fmaxf(M, meta[b * 32 + c].x);
        float L = 0.f;
        for (int c = 0; c < 32; c++) {
            float w = __expf(meta[b * 32 + c].x - M);
            wc[c] = w;
            L += w * meta[b * 32 + c].y;
        }
        Ls = L;
    }
    __syncthreads();
    float inv = 1.0f / Ls;
    float s0 = 0.f, s1 = 0.f;
#pragma unroll 4
    for (int c = 0; c < 32; c++) {
        const float* p = ctxp + ((size_t)b * 32 + c) * ND;
        float w = wc[c];
        s0 += w * p[tid];
        s1 += w * p[tid + 256];
    }
    out[b * ND + tid]       = s0 * inv;
    out[b * ND + tid + 256] = s1 * inv;
}

// ---------------------------------------------------------------------------
extern "C" void kernel_launch(void* const* d_in, const int* in_sizes, int n_in,
                              void* d_out, int out_size, void* d_ws, size_t ws_size,
                              hipStream_t stream)
{
    const float* q      = (const float*)d_in[0];   // [64][512]
    const float* values = (const float*)d_in[1];   // [64][2048][512]
    const float* W1     = (const float*)d_in[2];   // [512][256]
    const float* b1     = (const float*)d_in[3];   // [256]
    const float* W2     = (const float*)d_in[4];   // [512][256]
    const float* b2     = (const float*)d_in[5];   // [256]
    const float* V      = (const float*)d_in[6];   // [256]
    // d_in[7] = bV: uniform score shift -> softmax invariant, unused.

    char* ws = (char*)d_ws;
    float*  cb    = (float*) (ws);                 //  65536 B
    u16*    W1Tc  = (u16*)   (ws + 65536);         // 262144 B
    float*  ctxp  = (float*) (ws + 327680);        // 64*32*512*4 = 4 MB
    float2* meta  = (float2*)(ws + 327680 + 4194304);  // 16 KB

    hipLaunchKernelGGL(cbias_kernel, dim3(64), dim3(256), 0, stream, q, W2, b1, b2, cb);
    hipLaunchKernelGGL(transpose_kernel, dim3(8, 4), dim3(256), 0, stream, W1, W1Tc);
    hipLaunchKernelGGL(fused_kernel, dim3(2048), dim3(256), 0, stream,
                       values, W1Tc, cb, V, ctxp, meta);
    hipLaunchKernelGGL(combine_kernel, dim3(64), dim3(256), 0, stream,
                       ctxp, meta, (float*)d_out);
}